// Round 9
// baseline (683.644 us; speedup 1.0000x reference)
//
#include <hip/hip_runtime.h>
#include <hip/hip_bf16.h>

#define BB 16
#define NN 196
#define NP 224
#define CC 2048
#define C8 256
#define HH 4
#define DM 512
#define FF (CC*NN)   // 401408

typedef unsigned short u16;
typedef signed char s8;
typedef __attribute__((ext_vector_type(4))) u16 u16x4;
typedef __attribute__((ext_vector_type(8))) u16 u16x8;
typedef __attribute__((ext_vector_type(8))) short bf16x8;
typedef __attribute__((ext_vector_type(4))) float f32x4;
typedef __attribute__((ext_vector_type(4))) int i32x4;

typedef __attribute__((address_space(1))) unsigned int as1_uint;
typedef __attribute__((address_space(3))) unsigned int as3_uint;

__device__ __forceinline__ void cp16(void* l, const void* g) {
    __builtin_amdgcn_global_load_lds((as1_uint*)g, (as3_uint*)l, 16, 0, 0);
}

__device__ __forceinline__ u16 f2bf(float f) {
    union { float f; unsigned u; } x; x.f = f;
    unsigned r = x.u + 0x7FFF + ((x.u >> 16) & 1);
    return (u16)(r >> 16);
}
__device__ __forceinline__ float bf2f(u16 u) {
    union { unsigned u; float f; } x; x.u = ((unsigned)u) << 16;
    return x.f;
}
__device__ __forceinline__ int q8i(float v, float s) {
    int q = __float2int_rn(fminf(fmaxf(v * s, -127.f), 127.f));
    return q & 255;
}
__device__ __forceinline__ int pk4(float a, float b, float c, float d, float s) {
    return q8i(a, s) | (q8i(b, s) << 8) | (q8i(c, s) << 16) | (q8i(d, s) << 24);
}

#define QX (127.0f / 6.0f)
#define QW (127.0f / 0.15f)
#define SCL ((6.0f / 127.0f) * (0.15f / 127.0f))

// ---------------------------------------------------------------- k_prep
__global__ __launch_bounds__(256) void k_prep(const float* __restrict__ bef,
                                              const float* __restrict__ aft,
                                              u16* __restrict__ xhi, u16* __restrict__ xlo,
                                              u16* __restrict__ dhi, u16* __restrict__ dlo,
                                              s8* __restrict__ x8)
{
    const float inv3 = 1.0f / 3.0f;
    const size_t n4 = (size_t)BB * NN * CC / 4;   // 1605632
    const size_t stride = (size_t)gridDim.x * blockDim.x;
    for (size_t i = (size_t)blockIdx.x * blockDim.x + threadIdx.x; i < n4; i += stride) {
        float4 a = ((const float4*)aft)[i];
        float4 b = ((const float4*)bef)[i];
        float4 d;
        d.x = (a.x - b.x) * inv3; d.y = (a.y - b.y) * inv3;
        d.z = (a.z - b.z) * inv3; d.w = (a.w - b.w) * inv3;
        size_t bn = i >> 9;
        int c = (int)(i & 511) * 4;
        int b_ = (int)(bn / NN), n = (int)(bn % NN);
        size_t dof = ((size_t)b_ * NP + n) * CC + c;
        u16x4 h4, l4;
        h4.x = f2bf(d.x); l4.x = f2bf(d.x - bf2f(h4.x));
        h4.y = f2bf(d.y); l4.y = f2bf(d.y - bf2f(h4.y));
        h4.z = f2bf(d.z); l4.z = f2bf(d.z - bf2f(h4.z));
        h4.w = f2bf(d.w); l4.w = f2bf(d.w - bf2f(h4.w));
        *(u16x4*)(dhi + dof) = h4;
        *(u16x4*)(dlo + dof) = l4;
#pragma unroll
        for (int h = 0; h < HH; ++h) {
            float fh = (float)h;
            float4 x;
            x.x = b.x + fh * d.x; x.y = b.y + fh * d.y;
            x.z = b.z + fh * d.z; x.w = b.w + fh * d.w;
            size_t xof = ((size_t)(h * BB + b_) * NP + n) * CC + c;
            u16x4 xh4;
            xh4.x = f2bf(x.x); xh4.y = f2bf(x.y);
            xh4.z = f2bf(x.z); xh4.w = f2bf(x.w);
            *(u16x4*)(xhi + xof) = xh4;
            if (h != 0) {
                u16x4 xl4;
                xl4.x = f2bf(x.x - bf2f(xh4.x));
                xl4.y = f2bf(x.y - bf2f(xh4.y));
                xl4.z = f2bf(x.z - bf2f(xh4.z));
                xl4.w = f2bf(x.w - bf2f(xh4.w));
                *(u16x4*)(xlo + xof) = xl4;
            }
            *(int*)(x8 + xof) = pk4(x.x, x.y, x.z, x.w, QX);
        }
    }
    // zero pad rows
    const size_t dpad = (size_t)BB * (NP - NN) * CC / 4;      // 229376
    const u16x4 z4 = {0, 0, 0, 0};
    for (size_t i = (size_t)blockIdx.x * blockDim.x + threadIdx.x; i < dpad; i += stride) {
        size_t b_ = i / ((NP - NN) * CC / 4);
        size_t rem = i % ((NP - NN) * CC / 4);
        int pn = (int)(rem >> 9), c4 = (int)(rem & 511);
        size_t of = ((size_t)b_ * NP + NN + pn) * CC + c4 * 4;
        *(u16x4*)(dhi + of) = z4; *(u16x4*)(dlo + of) = z4;
    }
    const size_t xpad = (size_t)HH * BB * (NP - NN) * CC / 4; // 917504
    for (size_t i = (size_t)blockIdx.x * blockDim.x + threadIdx.x; i < xpad; i += stride) {
        size_t hb = i / ((NP - NN) * CC / 4);
        size_t rem = i % ((NP - NN) * CC / 4);
        int pn = (int)(rem >> 9), c4 = (int)(rem & 511);
        size_t of = ((size_t)hb * NP + NN + pn) * CC + c4 * 4;
        *(u16x4*)(xhi + of) = z4; *(u16x4*)(xlo + of) = z4;
        *(int*)(x8 + of) = 0;
    }
}

// ---------------------------------------------------------------- k_castW
__global__ __launch_bounds__(256) void k_castW(const float* __restrict__ Wq,
                                               const float* __restrict__ Wk,
                                               const float* __restrict__ Wv,
                                               u16* __restrict__ wqh, u16* __restrict__ wql,
                                               u16* __restrict__ wkh, u16* __restrict__ wkl,
                                               s8* __restrict__ Wv8)
{
    const size_t qk = (size_t)HH * C8 * CC / 4;     // 524288
    const size_t wv = (size_t)HH * CC * CC / 4;     // 4194304
    const size_t tot = qk * 2 + wv;
    const size_t stride = (size_t)gridDim.x * blockDim.x;
    for (size_t i = (size_t)blockIdx.x * blockDim.x + threadIdx.x; i < tot; i += stride) {
        if (i < qk * 2) {
            const float* src; u16* dh; u16* dl; size_t j;
            if (i < qk) { src = Wq; dh = wqh; dl = wql; j = i; }
            else        { src = Wk; dh = wkh; dl = wkl; j = i - qk; }
            float4 f = ((const float4*)src)[j];
            u16x4 h4, l4;
            h4.x = f2bf(f.x); l4.x = f2bf(f.x - bf2f(h4.x));
            h4.y = f2bf(f.y); l4.y = f2bf(f.y - bf2f(h4.y));
            h4.z = f2bf(f.z); l4.z = f2bf(f.z - bf2f(h4.z));
            h4.w = f2bf(f.w); l4.w = f2bf(f.w - bf2f(h4.w));
            ((u16x4*)dh)[j] = h4; ((u16x4*)dl)[j] = l4;
        } else {
            size_t j = i - qk * 2;
            float4 f = ((const float4*)Wv)[j];
            *(int*)(Wv8 + 4 * j) = pk4(f.x, f.y, f.z, f.w, QW);
        }
    }
}

// ---------------------------------------------------------------- k_qkm
// split-bf16 MFMA GEMM, BK=64, XCD-linear grid (384 blocks):
//   id = xid*96 + z*48 + j0, xid in 0..3 (ct=xid&1, mt=xid>>1 in {0,1})
//   id%8 = j0%8 -> all 8 blocks sharing hb-panel co-locate on one XCD
// z=0: Q = x_h @ Wq_h^T + bq ; z=1: K = h*(dif @ Wk_h^T) + bk  (h in 1..3)
// outputs hi/lo bf16, layout [hb][n 224][o 256]
__global__ __launch_bounds__(256, 2) void k_qkm(
    const u16* __restrict__ xhi, const u16* __restrict__ xlo,
    const u16* __restrict__ dhi, const u16* __restrict__ dlo,
    const u16* __restrict__ wqh, const u16* __restrict__ wql,
    const u16* __restrict__ wkh, const u16* __restrict__ wkl,
    const float* __restrict__ bq, const float* __restrict__ bk,
    u16* __restrict__ Qhb, u16* __restrict__ Qlb,
    u16* __restrict__ Khb, u16* __restrict__ Klb)
{
    // cells of 16B (BK=64): Wh [0,1024) Wl [1024,2048) Xh [2048,2944) Xl [2944,3840)
    __shared__ u16 lds[3840 * 8];
    u16* Wh = lds;
    u16* Wl_ = lds + 1024 * 8;
    u16* Xh = lds + 2048 * 8;
    u16* Xl = lds + 2944 * 8;

    const int t = threadIdx.x, w = t >> 6, ln = t & 63;
    const int lg = ln >> 4, l16 = ln & 15;
    const int id = blockIdx.x;
    const int xid = id / 96, rem = id % 96;
    const int z = rem / 48, j0 = rem % 48;
    const int hb = j0 + 16, h = hb >> 4, b = hb & 15;
    const int ct = xid & 1, mt = xid >> 1;   // mt in {0,1}

    const u16* Ah = (z ? dhi + (size_t)b * NP * CC : xhi + (size_t)hb * NP * CC)
                    + (size_t)(mt * 112) * CC;
    const u16* Al = (z ? dlo + (size_t)b * NP * CC : xlo + (size_t)hb * NP * CC)
                    + (size_t)(mt * 112) * CC;
    const u16* Bh = (z ? wkh : wqh) + ((size_t)h * C8 + ct * 128) * CC;
    const u16* Bl = (z ? wkl : wql) + ((size_t)h * C8 + ct * 128) * CC;
    const float scale = z ? (float)h : 1.0f;
    const float* bias = (z ? bk : bq) + h * C8;
    u16* OutH = z ? Khb : Qhb;
    u16* OutL = z ? Klb : Qlb;

    f32x4 acc[2][7];
    const f32x4 zf = {0.f, 0.f, 0.f, 0.f};
#pragma unroll
    for (int i = 0; i < 2; ++i)
#pragma unroll
        for (int j = 0; j < 7; ++j) acc[i][j] = zf;

    for (int k0 = 0; k0 < CC; k0 += 64) {
        // W cells: 1024 each buffer; cell c: g=c>>7 (0..7), o=c&127
#pragma unroll
        for (int it = 0; it < 4; ++it) {
            int cell = it * 256 + t;
            int g = cell >> 7, o = cell & 127;
            cp16(Wh + (size_t)cell * 8, Bh + (size_t)o * CC + k0 + 8 * g);
            cp16(Wl_ + (size_t)cell * 8, Bl + (size_t)o * CC + k0 + 8 * g);
        }
        // X cells: 896 each buffer; cell c: g=c/112 (0..7), n=c%112
#pragma unroll
        for (int it = 0; it < 4; ++it) {
            int cell = it * 256 + t;
            if (cell < 896) {
                int g = cell / 112, n = cell % 112;
                cp16(Xh + (size_t)cell * 8, Ah + (size_t)n * CC + k0 + 8 * g);
                cp16(Xl + (size_t)cell * 8, Al + (size_t)n * CC + k0 + 8 * g);
            }
        }
        __syncthreads();
#pragma unroll
        for (int s = 0; s < 2; ++s) {
            const int ga = s * 4 + lg;
            bf16x8 ah[2], al[2], bh[7], bl[7];
#pragma unroll
            for (int i = 0; i < 2; ++i) {
                ah[i] = *(const bf16x8*)(Wh + (size_t)(ga * 128 + w * 32 + i * 16 + l16) * 8);
                al[i] = *(const bf16x8*)(Wl_ + (size_t)(ga * 128 + w * 32 + i * 16 + l16) * 8);
            }
#pragma unroll
            for (int j = 0; j < 7; ++j) {
                bh[j] = *(const bf16x8*)(Xh + (size_t)(ga * 112 + j * 16 + l16) * 8);
                bl[j] = *(const bf16x8*)(Xl + (size_t)(ga * 112 + j * 16 + l16) * 8);
            }
#pragma unroll
            for (int i = 0; i < 2; ++i)
#pragma unroll
                for (int j = 0; j < 7; ++j)
                    acc[i][j] = __builtin_amdgcn_mfma_f32_16x16x32_bf16(ah[i], bh[j], acc[i][j], 0, 0, 0);
#pragma unroll
            for (int i = 0; i < 2; ++i)
#pragma unroll
                for (int j = 0; j < 7; ++j)
                    acc[i][j] = __builtin_amdgcn_mfma_f32_16x16x32_bf16(ah[i], bl[j], acc[i][j], 0, 0, 0);
#pragma unroll
            for (int i = 0; i < 2; ++i)
#pragma unroll
                for (int j = 0; j < 7; ++j)
                    acc[i][j] = __builtin_amdgcn_mfma_f32_16x16x32_bf16(al[i], bh[j], acc[i][j], 0, 0, 0);
        }
        __syncthreads();
    }

#pragma unroll
    for (int i = 0; i < 2; ++i) {
        int ob = ct * 128 + w * 32 + i * 16 + lg * 4;
#pragma unroll
        for (int j = 0; j < 7; ++j) {
            int n = mt * 112 + j * 16 + l16;
            u16x4 hv, lv;
#pragma unroll
            for (int r = 0; r < 4; ++r) {
                float v = scale * acc[i][j][r] + bias[ob + r];
                hv[r] = f2bf(v);
                lv[r] = f2bf(v - bf2f(hv[r]));
            }
            size_t of = ((size_t)hb * NP + n) * C8 + ob;
            *(u16x4*)(OutH + of) = hv;
            *(u16x4*)(OutL + of) = lv;
        }
    }
}

// ---------------------------------------------------------------- k_esm (MFMA)
// grid (hb 64, mt 4) so the 4 mt-blocks of one hb co-locate on an XCD.
__global__ __launch_bounds__(256, 2) void k_esm(
    const u16* __restrict__ Qh, const u16* __restrict__ Ql,
    const u16* __restrict__ Kh, const u16* __restrict__ Kl,
    float* __restrict__ alphas, u16* __restrict__ atnb)
{
    // cells of 16B: QH [0,256) QL [256,512) KH [512,1408) KL [1408,2304)
    __shared__ u16 lds[2304 * 8];
    u16* QHs = lds;
    u16* QLs = lds + 256 * 8;
    u16* KHs = lds + 512 * 8;
    u16* KLs = lds + 1408 * 8;

    const int t = threadIdx.x, w = t >> 6, ln = t & 63;
    const int lg = ln >> 4, l16 = ln & 15;
    const int hb = blockIdx.x, mt = blockIdx.y;
    const int h = hb >> 4, b = hb & 15;

    if (h == 0) {   // uniform attention
        const float uni = 1.0f / 196.0f;
        const u16 ub = f2bf(uni);
        for (int idx = t; idx < 64 * NP; idx += 256) {
            int m = mt * 64 + idx / NP;
            int n = idx % NP;
            if (m < NP) {
                atnb[((size_t)hb * NP + m) * NP + n] = (n < NN) ? ub : (u16)0;
                if (m < NN && n < NN)
                    alphas[(((size_t)b * NN + m) * NN + n) * HH + 0] = uni;
            }
        }
        return;
    }

    const size_t base = (size_t)hb * NP * C8;

    f32x4 e[14];
    const f32x4 zf = {0.f, 0.f, 0.f, 0.f};
#pragma unroll
    for (int j = 0; j < 14; ++j) e[j] = zf;

    for (int o0 = 0; o0 < C8; o0 += 32) {
        {
            int g = t >> 6, mr = t & 63;
            size_t src = base + (size_t)(mt * 64 + mr) * C8 + o0 + 8 * g;
            cp16(QHs + (size_t)t * 8, Qh + src);
            cp16(QLs + (size_t)t * 8, Ql + src);
        }
#pragma unroll
        for (int it = 0; it < 4; ++it) {
            int cell = it * 256 + t;
            if (cell < 896) {
                int g = cell / 224, n = cell % 224;
                size_t src = base + (size_t)n * C8 + o0 + 8 * g;
                cp16(KHs + (size_t)cell * 8, Kh + src);
                cp16(KLs + (size_t)cell * 8, Kl + src);
            }
        }
        __syncthreads();
        bf16x8 ah = *(const bf16x8*)(QHs + (size_t)(lg * 64 + w * 16 + l16) * 8);
        bf16x8 al = *(const bf16x8*)(QLs + (size_t)(lg * 64 + w * 16 + l16) * 8);
#pragma unroll
        for (int j = 0; j < 14; ++j) {
            bf16x8 bh = *(const bf16x8*)(KHs + (size_t)(lg * 224 + j * 16 + l16) * 8);
            bf16x8 bl = *(const bf16x8*)(KLs + (size_t)(lg * 224 + j * 16 + l16) * 8);
            e[j] = __builtin_amdgcn_mfma_f32_16x16x32_bf16(ah, bh, e[j], 0, 0, 0);
            e[j] = __builtin_amdgcn_mfma_f32_16x16x32_bf16(ah, bl, e[j], 0, 0, 0);
            e[j] = __builtin_amdgcn_mfma_f32_16x16x32_bf16(al, bh, e[j], 0, 0, 0);
        }
        __syncthreads();
    }

#pragma unroll
    for (int r = 0; r < 4; ++r) {
        float mx = -1e30f;
#pragma unroll
        for (int j = 0; j < 14; ++j) {
            int n = j * 16 + l16;
            if (n < NN) mx = fmaxf(mx, e[j][r]);
        }
#pragma unroll
        for (int off = 1; off <= 8; off <<= 1) mx = fmaxf(mx, __shfl_xor(mx, off));
        float p[14];
        float s = 0.f;
#pragma unroll
        for (int j = 0; j < 14; ++j) {
            int n = j * 16 + l16;
            if (n < NN) { p[j] = __expf(e[j][r] - mx); s += p[j]; }
            else p[j] = 0.f;
        }
#pragma unroll
        for (int off = 1; off <= 8; off <<= 1) s += __shfl_xor(s, off);
        const float inv = 1.0f / s;
        const int m = mt * 64 + w * 16 + lg * 4 + r;
        if (m < NP) {
            u16* arow = atnb + ((size_t)hb * NP + m) * NP;
#pragma unroll
            for (int j = 0; j < 14; ++j) {
                int n = j * 16 + l16;
                float a = p[j] * inv;
                arow[n] = f2bf(a);
                if (m < NN && n < NN)
                    alphas[(((size_t)b * NN + m) * NN + n) * HH + h] = a;
            }
        }
    }
}

// ---------------------------------------------------------------- k_vpv
// linear grid 1024: id = ct*64 + hb (id%8 = hb%8 -> ct-blocks of one hb co-XCD)
__global__ __launch_bounds__(256, 2) void k_vpv(
    const s8* __restrict__ Wv8,    // [h][2048][2048] int8
    const s8* __restrict__ x8,     // [h][b][224][2048] int8
    const u16* __restrict__ xhi,   // [h][b][224][2048] bf16 (residual)
    const u16* __restrict__ atnb,  // [h][b][224][224] bf16
    const float* __restrict__ bv,
    const float* __restrict__ gamma,
    u16* __restrict__ outs)        // [h][b][2048][196] bf16
{
    __shared__ u16 lds[4992 * 8];
    s8* Aw8 = (s8*)lds;            // 512 cells * 16B
    s8* Bx8 = (s8*)lds + 8192;     // 896 cells * 16B
    u16* BxP = lds + 512 * 8;      // phase-2 P staging (aliases Bx8)
    u16* Vb  = lds + 1408 * 8;     // bf16 V park

    const int t = threadIdx.x, w = t >> 6, ln = t & 63;
    const int lg = ln >> 4, l16 = ln & 15;
    const int wr = w >> 1, wc = w & 1;
    const int id = blockIdx.x;
    const int ct = id >> 6, hb = id & 63;
    const int h = hb >> 4, b = hb & 15;
    const size_t wv_base = ((size_t)h * CC + ct * 128) * CC;
    const size_t x8_base = (size_t)(h * BB + b) * NP * CC;
    const size_t xh_base = x8_base;
    const size_t p_base  = (size_t)(h * BB + b) * NP * NP;

    // phase 1: V = Wv @ x (int8, K-step 64)
    i32x4 acc8[4][7];
    const i32x4 zi = {0, 0, 0, 0};
#pragma unroll
    for (int i = 0; i < 4; ++i)
#pragma unroll
        for (int j = 0; j < 7; ++j) acc8[i][j] = zi;

    for (int k0 = 0; k0 < CC; k0 += 64) {
#pragma unroll
        for (int it = 0; it < 2; ++it) {
            int cell = it * 256 + t;
            int g = cell >> 7, o = cell & 127;
            cp16(Aw8 + (size_t)cell * 16, Wv8 + wv_base + (size_t)o * CC + k0 + 16 * g);
        }
#pragma unroll
        for (int it = 0; it < 4; ++it) {
            int cell = it * 256 + t;
            if (cell < 896) {
                int g = cell / NP, n = cell % NP;
                cp16(Bx8 + (size_t)cell * 16, x8 + x8_base + (size_t)n * CC + k0 + 16 * g);
            }
        }
        __syncthreads();
        i32x4 a8[4], b8[7];
#pragma unroll
        for (int i = 0; i < 4; ++i)
            a8[i] = *(const i32x4*)(Aw8 + (size_t)(lg * 128 + wr * 64 + i * 16 + l16) * 16);
#pragma unroll
        for (int j = 0; j < 7; ++j)
            b8[j] = *(const i32x4*)(Bx8 + (size_t)(lg * NP + wc * 112 + j * 16 + l16) * 16);
#pragma unroll
        for (int i = 0; i < 4; ++i)
#pragma unroll
            for (int j = 0; j < 7; ++j)
                acc8[i][j] = __builtin_amdgcn_mfma_i32_16x16x64_i8(a8[i], b8[j], acc8[i][j], 0, 0, 0);
        __syncthreads();
    }

    // park V (dequant + bias) in LDS as bf16
#pragma unroll
    for (int i = 0; i < 4; ++i) {
        int cb = wr * 64 + i * 16 + lg * 4;
#pragma unroll
        for (int j = 0; j < 7; ++j) {
            int n = wc * 112 + j * 16 + l16;
#pragma unroll
            for (int r = 0; r < 4; ++r) {
                float v = (float)acc8[i][j][r] * SCL + bv[h * CC + ct * 128 + cb + r];
                Vb[(size_t)((n >> 3) * 128 + cb + r) * 8 + (n & 7)] = f2bf(v);
            }
        }
    }
    __syncthreads();

    // phase 2: out = V @ P^T (bf16)
    f32x4 acc[4][7];
    const f32x4 zf = {0.f, 0.f, 0.f, 0.f};
#pragma unroll
    for (int i = 0; i < 4; ++i)
#pragma unroll
        for (int j = 0; j < 7; ++j) acc[i][j] = zf;

    for (int s = 0; s < 7; ++s) {
#pragma unroll
        for (int it = 0; it < 4; ++it) {
            if (it < 3 || w < 2) {
                int cell = it * 256 + w * 64 + ln;
                int g = cell / NP, m = cell % NP;
                cp16(BxP + (size_t)cell * 8, atnb + p_base + (size_t)m * NP + s * 32 + 8 * g);
            }
        }
        __syncthreads();
        bf16x8 a[4], bq[7];
#pragma unroll
        for (int i = 0; i < 4; ++i)
            a[i] = *(const bf16x8*)(Vb + (size_t)((4 * s + lg) * 128 + wr * 64 + i * 16 + l16) * 8);
#pragma unroll
        for (int j = 0; j < 7; ++j)
            bq[j] = *(const bf16x8*)(BxP + (size_t)(lg * NP + wc * 112 + j * 16 + l16) * 8);
#pragma unroll
        for (int i = 0; i < 4; ++i)
#pragma unroll
            for (int j = 0; j < 7; ++j)
                acc[i][j] = __builtin_amdgcn_mfma_f32_16x16x32_bf16(a[i], bq[j], acc[i][j], 0, 0, 0);
        __syncthreads();
    }

    // epilogue
    const float gm = gamma[h];
    const size_t ob = ((size_t)(h * BB + b) * CC + ct * 128) * NN;
#pragma unroll
    for (int i = 0; i < 4; ++i) {
        int cb = wr * 64 + i * 16 + lg * 4;
#pragma unroll
        for (int j = 0; j < 7; ++j) {
            int m = wc * 112 + j * 16 + l16;
            if (m < NN) {
                const u16* xp = xhi + xh_base + (size_t)m * CC + ct * 128 + cb;
#pragma unroll
                for (int r = 0; r < 4; ++r) {
                    float ov = gm * acc[i][j][r] + bf2f(xp[r]);
                    outs[ob + (size_t)(cb + r) * NN + m] = f2bf(ov);
                }
            }
        }
    }
}

// ---------------------------------------------------------------- k_lin (MFMA, split-K)
__global__ __launch_bounds__(256, 2) void k_lin(
    const u16* __restrict__ feats, const float* __restrict__ Wl,
    float* __restrict__ part)
{
    __shared__ u16 lds[(256 + 1040) * 8];
    u16* Aa = lds;
    u16* Bb = lds + 256 * 8;
    const int t = threadIdx.x, w = t >> 6, ln = t & 63;
    const int lg = ln >> 4, l16 = ln & 15;
    const int wr = w >> 1, wc = w & 1;      // wave tile: 32 a x 128 dm
    const int dmt = blockIdx.x, ch = blockIdx.y;
    const int ga = t >> 6, aa = t & 63;
    const u16* asrc = feats + (size_t)((aa & 3) * BB + (aa >> 2)) * FF + (size_t)ch * 1568 + 8 * ga;
    const float* bsrc = Wl + ((size_t)dmt * 256 + t) * FF + (size_t)ch * 1568;

    f32x4 acc[2][8];
    const f32x4 zf = {0.f, 0.f, 0.f, 0.f};
#pragma unroll
    for (int i = 0; i < 2; ++i)
#pragma unroll
        for (int j = 0; j < 8; ++j) acc[i][j] = zf;

    for (int k0 = 0; k0 < 1568; k0 += 32) {
        cp16(Aa + (size_t)t * 8, asrc + k0);
#pragma unroll
        for (int g = 0; g < 4; ++g) {
            float4 f0 = *(const float4*)(bsrc + k0 + 8 * g);
            float4 f1 = *(const float4*)(bsrc + k0 + 8 * g + 4);
            u16x8 bb;
            bb.s0 = f2bf(f0.x); bb.s1 = f2bf(f0.y); bb.s2 = f2bf(f0.z); bb.s3 = f2bf(f0.w);
            bb.s4 = f2bf(f1.x); bb.s5 = f2bf(f1.y); bb.s6 = f2bf(f1.z); bb.s7 = f2bf(f1.w);
            *(u16x8*)(Bb + (size_t)(g * 260 + t) * 8) = bb;
        }
        __syncthreads();
        bf16x8 a[2], bq[8];
#pragma unroll
        for (int i = 0; i < 2; ++i)
            a[i] = *(const bf16x8*)(Aa + (size_t)(lg * 64 + wr * 32 + i * 16 + l16) * 8);
#pragma unroll
        for (int j = 0; j < 8; ++j)
            bq[j] = *(const bf16x8*)(Bb + (size_t)(lg * 260 + wc * 128 + j * 16 + l16) * 8);
#pragma unroll
        for (int i = 0; i < 2; ++i)
#pragma unroll
            for (int j = 0; j < 8; ++j)
                acc[i][j] = __builtin_amdgcn_mfma_f32_16x16x32_bf16(a[i], bq[j], acc[i][j], 0, 0, 0);
        __syncthreads();
    }
#pragma unroll
    for (int i = 0; i < 2; ++i)
#pragma unroll
        for (int j = 0; j < 8; ++j)
#pragma unroll
            for (int r = 0; r < 4; ++r)
                part[((size_t)ch * 64 + wr * 32 + i * 16 + lg * 4 + r) * DM
                     + dmt * 256 + wc * 128 + j * 16 + l16] = acc[i][j][r];
}

// ---------------------------------------------------------------- k_red
__global__ __launch_bounds__(256) void k_red(const float* __restrict__ part,
                                             const float* __restrict__ bl,
                                             float* __restrict__ out0)
{
    int gid = blockIdx.x * 256 + threadIdx.x;
    if (gid < 64 * DM) {
        int dm = gid & (DM - 1);
        float s = bl[dm];
        for (int c2 = 0; c2 < 256; ++c2) s += part[(size_t)c2 * 64 * DM + gid];
        out0[gid] = s;
    }
}

// ---------------------------------------------------------------- launch
extern "C" void kernel_launch(void* const* d_in, const int* in_sizes, int n_in,
                              void* d_out, int out_size, void* d_ws, size_t ws_size,
                              hipStream_t stream)
{
    const float* bef   = (const float*)d_in[0];
    const float* aft   = (const float*)d_in[1];
    const float* Wq    = (const float*)d_in[2];
    const float* bq    = (const float*)d_in[3];
    const float* Wk    = (const float*)d_in[4];
    const float* bk    = (const float*)d_in[5];
    const float* Wv    = (const float*)d_in[6];
    const float* bv    = (const float*)d_in[7];
    const float* gamma = (const float*)d_in[8];
    const float* Wl    = (const float*)d_in[9];
    const float* bl    = (const float*)d_in[10];

    float* out0   = (float*)d_out;
    float* alphas = out0 + (size_t)BB * HH * DM;

    float* ws = (float*)d_ws;
    u16* xhi  = (u16*)ws;                        // 14,680,064
    u16* xlo  = (u16*)(ws + 14680064);           // 14,680,064
    u16* dhi  = (u16*)(ws + 29360128);           //  3,670,016
    u16* dlo  = (u16*)(ws + 33030144);           //  3,670,016
    u16* wqh  = (u16*)(ws + 36700160);           //  1,048,576
    u16* wql  = (u16*)(ws + 37748736);
    u16* wkh  = (u16*)(ws + 38797312);
    u16* wkl  = (u16*)(ws + 39845888);
    u16* Qhb  = (u16*)(ws + 40894464);           //  1,835,008 each
    u16* Qlb  = (u16*)(ws + 42729472);
    u16* Khb  = (u16*)(ws + 44564480);
    u16* Klb  = (u16*)(ws + 46399488);
    s8*  Wv8  = (s8*)(ws + 48234496);            //  4,194,304
    s8*  x8   = (s8*)(ws + 52428800);            //  7,340,032
    u16* atnb = (u16*)(ws + 59768832);           //  1,605,632
    u16* outs = (u16*)(ws + 61374464);           // 12,845,056
    float* part = ws + 74219520;                 //  8,388,608 -> end 82,608,128

    k_prep<<<2048, 256, 0, stream>>>(bef, aft, xhi, xlo, dhi, dlo, x8);
    k_castW<<<2048, 256, 0, stream>>>(Wq, Wk, Wv, wqh, wql, wkh, wkl, Wv8);
    k_qkm<<<384, 256, 0, stream>>>(xhi, xlo, dhi, dlo, wqh, wql, wkh, wkl,
                                   bq, bk, Qhb, Qlb, Khb, Klb);
    k_esm<<<dim3(64, 4), 256, 0, stream>>>(Qhb, Qlb, Khb, Klb, alphas, atnb);
    k_vpv<<<1024, 256, 0, stream>>>(Wv8, x8, xhi, atnb, bv, gamma, outs);
    k_lin<<<dim3(2, 256), 256, 0, stream>>>(outs, Wl, part);
    k_red<<<128, 256, 0, stream>>>(part, bl, out0);
}

// Round 10
// 581.479 us; speedup vs baseline: 1.1757x; 1.1757x over previous
//
#include <hip/hip_runtime.h>
#include <hip/hip_bf16.h>

#define BB 16
#define NN 196
#define NP 224
#define CC 2048
#define C8 256
#define HH 4
#define DM 512
#define FF (CC*NN)   // 401408

typedef unsigned short u16;
typedef signed char s8;
typedef __attribute__((ext_vector_type(4))) u16 u16x4;
typedef __attribute__((ext_vector_type(8))) u16 u16x8;
typedef __attribute__((ext_vector_type(8))) short bf16x8;
typedef __attribute__((ext_vector_type(4))) float f32x4;
typedef __attribute__((ext_vector_type(4))) int i32x4;

typedef __attribute__((address_space(1))) unsigned int as1_uint;
typedef __attribute__((address_space(3))) unsigned int as3_uint;

__device__ __forceinline__ void cp16(void* l, const void* g) {
    __builtin_amdgcn_global_load_lds((as1_uint*)g, (as3_uint*)l, 16, 0, 0);
}

__device__ __forceinline__ u16 f2bf(float f) {
    union { float f; unsigned u; } x; x.f = f;
    unsigned r = x.u + 0x7FFF + ((x.u >> 16) & 1);
    return (u16)(r >> 16);
}
__device__ __forceinline__ float bf2f(u16 u) {
    union { unsigned u; float f; } x; x.u = ((unsigned)u) << 16;
    return x.f;
}
__device__ __forceinline__ int q8i(float v, float s) {
    int q = __float2int_rn(fminf(fmaxf(v * s, -127.f), 127.f));
    return q & 255;
}
__device__ __forceinline__ int pk4(float a, float b, float c, float d, float s) {
    return q8i(a, s) | (q8i(b, s) << 8) | (q8i(c, s) << 16) | (q8i(d, s) << 24);
}

#define QX (127.0f / 6.0f)
#define QW (127.0f / 0.15f)
#define SCL ((6.0f / 127.0f) * (0.15f / 127.0f))

// ---------------------------------------------------------------- k_prep
__global__ __launch_bounds__(256) void k_prep(const float* __restrict__ bef,
                                              const float* __restrict__ aft,
                                              u16* __restrict__ xhi, u16* __restrict__ xlo,
                                              u16* __restrict__ dhi, u16* __restrict__ dlo,
                                              s8* __restrict__ x8)
{
    const float inv3 = 1.0f / 3.0f;
    const size_t n4 = (size_t)BB * NN * CC / 4;   // 1605632
    const size_t stride = (size_t)gridDim.x * blockDim.x;
    for (size_t i = (size_t)blockIdx.x * blockDim.x + threadIdx.x; i < n4; i += stride) {
        float4 a = ((const float4*)aft)[i];
        float4 b = ((const float4*)bef)[i];
        float4 d;
        d.x = (a.x - b.x) * inv3; d.y = (a.y - b.y) * inv3;
        d.z = (a.z - b.z) * inv3; d.w = (a.w - b.w) * inv3;
        size_t bn = i >> 9;
        int c = (int)(i & 511) * 4;
        int b_ = (int)(bn / NN), n = (int)(bn % NN);
        size_t dof = ((size_t)b_ * NP + n) * CC + c;
        u16x4 h4, l4;
        h4.x = f2bf(d.x); l4.x = f2bf(d.x - bf2f(h4.x));
        h4.y = f2bf(d.y); l4.y = f2bf(d.y - bf2f(h4.y));
        h4.z = f2bf(d.z); l4.z = f2bf(d.z - bf2f(h4.z));
        h4.w = f2bf(d.w); l4.w = f2bf(d.w - bf2f(h4.w));
        *(u16x4*)(dhi + dof) = h4;
        *(u16x4*)(dlo + dof) = l4;
#pragma unroll
        for (int h = 0; h < HH; ++h) {
            float fh = (float)h;
            float4 x;
            x.x = b.x + fh * d.x; x.y = b.y + fh * d.y;
            x.z = b.z + fh * d.z; x.w = b.w + fh * d.w;
            size_t xof = ((size_t)(h * BB + b_) * NP + n) * CC + c;
            u16x4 xh4;
            xh4.x = f2bf(x.x); xh4.y = f2bf(x.y);
            xh4.z = f2bf(x.z); xh4.w = f2bf(x.w);
            *(u16x4*)(xhi + xof) = xh4;
            if (h != 0) {
                u16x4 xl4;
                xl4.x = f2bf(x.x - bf2f(xh4.x));
                xl4.y = f2bf(x.y - bf2f(xh4.y));
                xl4.z = f2bf(x.z - bf2f(xh4.z));
                xl4.w = f2bf(x.w - bf2f(xh4.w));
                *(u16x4*)(xlo + xof) = xl4;
            }
            *(int*)(x8 + xof) = pk4(x.x, x.y, x.z, x.w, QX);
        }
    }
    // zero pad rows
    const size_t dpad = (size_t)BB * (NP - NN) * CC / 4;      // 229376
    const u16x4 z4 = {0, 0, 0, 0};
    for (size_t i = (size_t)blockIdx.x * blockDim.x + threadIdx.x; i < dpad; i += stride) {
        size_t b_ = i / ((NP - NN) * CC / 4);
        size_t rem = i % ((NP - NN) * CC / 4);
        int pn = (int)(rem >> 9), c4 = (int)(rem & 511);
        size_t of = ((size_t)b_ * NP + NN + pn) * CC + c4 * 4;
        *(u16x4*)(dhi + of) = z4; *(u16x4*)(dlo + of) = z4;
    }
    const size_t xpad = (size_t)HH * BB * (NP - NN) * CC / 4; // 917504
    for (size_t i = (size_t)blockIdx.x * blockDim.x + threadIdx.x; i < xpad; i += stride) {
        size_t hb = i / ((NP - NN) * CC / 4);
        size_t rem = i % ((NP - NN) * CC / 4);
        int pn = (int)(rem >> 9), c4 = (int)(rem & 511);
        size_t of = ((size_t)hb * NP + NN + pn) * CC + c4 * 4;
        *(u16x4*)(xhi + of) = z4; *(u16x4*)(xlo + of) = z4;
        *(int*)(x8 + of) = 0;
    }
}

// ---------------------------------------------------------------- k_castW
__global__ __launch_bounds__(256) void k_castW(const float* __restrict__ Wq,
                                               const float* __restrict__ Wk,
                                               const float* __restrict__ Wv,
                                               u16* __restrict__ wqh, u16* __restrict__ wql,
                                               u16* __restrict__ wkh, u16* __restrict__ wkl,
                                               s8* __restrict__ Wv8)
{
    const size_t qk = (size_t)HH * C8 * CC / 4;     // 524288
    const size_t wv = (size_t)HH * CC * CC / 4;     // 4194304
    const size_t tot = qk * 2 + wv;
    const size_t stride = (size_t)gridDim.x * blockDim.x;
    for (size_t i = (size_t)blockIdx.x * blockDim.x + threadIdx.x; i < tot; i += stride) {
        if (i < qk * 2) {
            const float* src; u16* dh; u16* dl; size_t j;
            if (i < qk) { src = Wq; dh = wqh; dl = wql; j = i; }
            else        { src = Wk; dh = wkh; dl = wkl; j = i - qk; }
            float4 f = ((const float4*)src)[j];
            u16x4 h4, l4;
            h4.x = f2bf(f.x); l4.x = f2bf(f.x - bf2f(h4.x));
            h4.y = f2bf(f.y); l4.y = f2bf(f.y - bf2f(h4.y));
            h4.z = f2bf(f.z); l4.z = f2bf(f.z - bf2f(h4.z));
            h4.w = f2bf(f.w); l4.w = f2bf(f.w - bf2f(h4.w));
            ((u16x4*)dh)[j] = h4; ((u16x4*)dl)[j] = l4;
        } else {
            size_t j = i - qk * 2;
            float4 f = ((const float4*)Wv)[j];
            *(int*)(Wv8 + 4 * j) = pk4(f.x, f.y, f.z, f.w, QW);
        }
    }
}

// ---------------------------------------------------------------- k_qkm
// split-bf16 MFMA GEMM, BK=32 (round-7 proven staging), linear grid 384:
//   id = xid*96 + z*48 + j0, xid in 0..3 (ct=xid&1, mt=xid>>1)
// z=0: Q = x_h @ Wq_h^T + bq ; z=1: K = h*(dif @ Wk_h^T) + bk  (h in 1..3)
// outputs hi/lo bf16, layout [hb][n 224][o 256]
__global__ __launch_bounds__(256, 2) void k_qkm(
    const u16* __restrict__ xhi, const u16* __restrict__ xlo,
    const u16* __restrict__ dhi, const u16* __restrict__ dlo,
    const u16* __restrict__ wqh, const u16* __restrict__ wql,
    const u16* __restrict__ wkh, const u16* __restrict__ wkl,
    const float* __restrict__ bq, const float* __restrict__ bk,
    u16* __restrict__ Qhb, u16* __restrict__ Qlb,
    u16* __restrict__ Khb, u16* __restrict__ Klb)
{
    // cells of 16B: Wh [0,512) Wl [512,1024) Xh [1024,1472) Xl [1472,1920)
    __shared__ u16 lds[1920 * 8];
    u16* Wh = lds;
    u16* Wl_ = lds + 512 * 8;
    u16* Xh = lds + 1024 * 8;
    u16* Xl = lds + 1472 * 8;

    const int t = threadIdx.x, w = t >> 6, ln = t & 63;
    const int lg = ln >> 4, l16 = ln & 15;
    const int id = blockIdx.x;
    const int xid = id / 96, rem = id % 96;
    const int z = rem / 48, j0 = rem % 48;
    const int hb = j0 + 16, h = hb >> 4, b = hb & 15;
    const int ct = xid & 1, mt = xid >> 1;   // mt in {0,1}

    const u16* Ah = (z ? dhi + (size_t)b * NP * CC : xhi + (size_t)hb * NP * CC)
                    + (size_t)(mt * 112) * CC;
    const u16* Al = (z ? dlo + (size_t)b * NP * CC : xlo + (size_t)hb * NP * CC)
                    + (size_t)(mt * 112) * CC;
    const u16* Bh = (z ? wkh : wqh) + ((size_t)h * C8 + ct * 128) * CC;
    const u16* Bl = (z ? wkl : wql) + ((size_t)h * C8 + ct * 128) * CC;
    const float scale = z ? (float)h : 1.0f;
    const float* bias = (z ? bk : bq) + h * C8;
    u16* OutH = z ? Khb : Qhb;
    u16* OutL = z ? Klb : Qlb;

    f32x4 acc[2][7];
    const f32x4 zf = {0.f, 0.f, 0.f, 0.f};
#pragma unroll
    for (int i = 0; i < 2; ++i)
#pragma unroll
        for (int j = 0; j < 7; ++j) acc[i][j] = zf;

    for (int k0 = 0; k0 < CC; k0 += 32) {
#pragma unroll
        for (int it = 0; it < 2; ++it) {
            int cell = it * 256 + t;
            int g = cell >> 7, o = cell & 127;
            cp16(Wh + (size_t)cell * 8, Bh + (size_t)o * CC + k0 + 8 * g);
            cp16(Wl_ + (size_t)cell * 8, Bl + (size_t)o * CC + k0 + 8 * g);
        }
        {
            int g = t / 112, n = t % 112;
            cp16(Xh + (size_t)t * 8, Ah + (size_t)n * CC + k0 + 8 * g);
            cp16(Xl + (size_t)t * 8, Al + (size_t)n * CC + k0 + 8 * g);
            if (t < 192) {
                int cell = 256 + t;
                int g2 = cell / 112, n2 = cell % 112;
                cp16(Xh + (size_t)cell * 8, Ah + (size_t)n2 * CC + k0 + 8 * g2);
                cp16(Xl + (size_t)cell * 8, Al + (size_t)n2 * CC + k0 + 8 * g2);
            }
        }
        __syncthreads();
        bf16x8 ah[2], al[2], bh[7], bl[7];
#pragma unroll
        for (int i = 0; i < 2; ++i) {
            ah[i] = *(const bf16x8*)(Wh + (size_t)(lg * 128 + w * 32 + i * 16 + l16) * 8);
            al[i] = *(const bf16x8*)(Wl_ + (size_t)(lg * 128 + w * 32 + i * 16 + l16) * 8);
        }
#pragma unroll
        for (int j = 0; j < 7; ++j) {
            bh[j] = *(const bf16x8*)(Xh + (size_t)(lg * 112 + j * 16 + l16) * 8);
            bl[j] = *(const bf16x8*)(Xl + (size_t)(lg * 112 + j * 16 + l16) * 8);
        }
#pragma unroll
        for (int i = 0; i < 2; ++i)
#pragma unroll
            for (int j = 0; j < 7; ++j)
                acc[i][j] = __builtin_amdgcn_mfma_f32_16x16x32_bf16(ah[i], bh[j], acc[i][j], 0, 0, 0);
#pragma unroll
        for (int i = 0; i < 2; ++i)
#pragma unroll
            for (int j = 0; j < 7; ++j)
                acc[i][j] = __builtin_amdgcn_mfma_f32_16x16x32_bf16(ah[i], bl[j], acc[i][j], 0, 0, 0);
#pragma unroll
        for (int i = 0; i < 2; ++i)
#pragma unroll
            for (int j = 0; j < 7; ++j)
                acc[i][j] = __builtin_amdgcn_mfma_f32_16x16x32_bf16(al[i], bh[j], acc[i][j], 0, 0, 0);
        __syncthreads();
    }

#pragma unroll
    for (int i = 0; i < 2; ++i) {
        int ob = ct * 128 + w * 32 + i * 16 + lg * 4;
#pragma unroll
        for (int j = 0; j < 7; ++j) {
            int n = mt * 112 + j * 16 + l16;
            u16x4 hv, lv;
#pragma unroll
            for (int r = 0; r < 4; ++r) {
                float v = scale * acc[i][j][r] + bias[ob + r];
                hv[r] = f2bf(v);
                lv[r] = f2bf(v - bf2f(hv[r]));
            }
            size_t of = ((size_t)hb * NP + n) * C8 + ob;
            *(u16x4*)(OutH + of) = hv;
            *(u16x4*)(OutL + of) = lv;
        }
    }
}

// ---------------------------------------------------------------- k_esm (MFMA)
__global__ __launch_bounds__(256, 2) void k_esm(
    const u16* __restrict__ Qh, const u16* __restrict__ Ql,
    const u16* __restrict__ Kh, const u16* __restrict__ Kl,
    float* __restrict__ alphas, u16* __restrict__ atnb)
{
    // cells of 16B: QH [0,256) QL [256,512) KH [512,1408) KL [1408,2304)
    __shared__ u16 lds[2304 * 8];
    u16* QHs = lds;
    u16* QLs = lds + 256 * 8;
    u16* KHs = lds + 512 * 8;
    u16* KLs = lds + 1408 * 8;

    const int t = threadIdx.x, w = t >> 6, ln = t & 63;
    const int lg = ln >> 4, l16 = ln & 15;
    const int hb = blockIdx.x, mt = blockIdx.y;
    const int h = hb >> 4, b = hb & 15;

    if (h == 0) {   // uniform attention
        const float uni = 1.0f / 196.0f;
        const u16 ub = f2bf(uni);
        for (int idx = t; idx < 64 * NP; idx += 256) {
            int m = mt * 64 + idx / NP;
            int n = idx % NP;
            if (m < NP) {
                atnb[((size_t)hb * NP + m) * NP + n] = (n < NN) ? ub : (u16)0;
                if (m < NN && n < NN)
                    alphas[(((size_t)b * NN + m) * NN + n) * HH + 0] = uni;
            }
        }
        return;
    }

    const size_t base = (size_t)hb * NP * C8;

    f32x4 e[14];
    const f32x4 zf = {0.f, 0.f, 0.f, 0.f};
#pragma unroll
    for (int j = 0; j < 14; ++j) e[j] = zf;

    for (int o0 = 0; o0 < C8; o0 += 32) {
        {
            int g = t >> 6, mr = t & 63;
            size_t src = base + (size_t)(mt * 64 + mr) * C8 + o0 + 8 * g;
            cp16(QHs + (size_t)t * 8, Qh + src);
            cp16(QLs + (size_t)t * 8, Ql + src);
        }
#pragma unroll
        for (int it = 0; it < 4; ++it) {
            int cell = it * 256 + t;
            if (cell < 896) {
                int g = cell / 224, n = cell % 224;
                size_t src = base + (size_t)n * C8 + o0 + 8 * g;
                cp16(KHs + (size_t)cell * 8, Kh + src);
                cp16(KLs + (size_t)cell * 8, Kl + src);
            }
        }
        __syncthreads();
        bf16x8 ah = *(const bf16x8*)(QHs + (size_t)(lg * 64 + w * 16 + l16) * 8);
        bf16x8 al = *(const bf16x8*)(QLs + (size_t)(lg * 64 + w * 16 + l16) * 8);
#pragma unroll
        for (int j = 0; j < 14; ++j) {
            bf16x8 bh = *(const bf16x8*)(KHs + (size_t)(lg * 224 + j * 16 + l16) * 8);
            bf16x8 bl = *(const bf16x8*)(KLs + (size_t)(lg * 224 + j * 16 + l16) * 8);
            e[j] = __builtin_amdgcn_mfma_f32_16x16x32_bf16(ah, bh, e[j], 0, 0, 0);
            e[j] = __builtin_amdgcn_mfma_f32_16x16x32_bf16(ah, bl, e[j], 0, 0, 0);
            e[j] = __builtin_amdgcn_mfma_f32_16x16x32_bf16(al, bh, e[j], 0, 0, 0);
        }
        __syncthreads();
    }

#pragma unroll
    for (int r = 0; r < 4; ++r) {
        float mx = -1e30f;
#pragma unroll
        for (int j = 0; j < 14; ++j) {
            int n = j * 16 + l16;
            if (n < NN) mx = fmaxf(mx, e[j][r]);
        }
#pragma unroll
        for (int off = 1; off <= 8; off <<= 1) mx = fmaxf(mx, __shfl_xor(mx, off));
        float p[14];
        float s = 0.f;
#pragma unroll
        for (int j = 0; j < 14; ++j) {
            int n = j * 16 + l16;
            if (n < NN) { p[j] = __expf(e[j][r] - mx); s += p[j]; }
            else p[j] = 0.f;
        }
#pragma unroll
        for (int off = 1; off <= 8; off <<= 1) s += __shfl_xor(s, off);
        const float inv = 1.0f / s;
        const int m = mt * 64 + w * 16 + lg * 4 + r;
        if (m < NP) {
            u16* arow = atnb + ((size_t)hb * NP + m) * NP;
#pragma unroll
            for (int j = 0; j < 14; ++j) {
                int n = j * 16 + l16;
                float a = p[j] * inv;
                arow[n] = f2bf(a);
                if (m < NN && n < NN)
                    alphas[(((size_t)b * NN + m) * NN + n) * HH + h] = a;
            }
        }
    }
}

// ---------------------------------------------------------------- k_vpv
__global__ __launch_bounds__(256, 2) void k_vpv(
    const s8* __restrict__ Wv8,    // [h][2048][2048] int8
    const s8* __restrict__ x8,     // [h][b][224][2048] int8
    const u16* __restrict__ xhi,   // [h][b][224][2048] bf16 (residual)
    const u16* __restrict__ atnb,  // [h][b][224][224] bf16
    const float* __restrict__ bv,
    const float* __restrict__ gamma,
    u16* __restrict__ outs)        // [h][b][2048][196] bf16
{
    __shared__ u16 lds[4992 * 8];
    s8* Aw8 = (s8*)lds;            // 512 cells * 16B
    s8* Bx8 = (s8*)lds + 8192;     // 896 cells * 16B
    u16* BxP = lds + 512 * 8;      // phase-2 P staging (aliases Bx8)
    u16* Vb  = lds + 1408 * 8;     // bf16 V park

    const int t = threadIdx.x, w = t >> 6, ln = t & 63;
    const int lg = ln >> 4, l16 = ln & 15;
    const int wr = w >> 1, wc = w & 1;
    const int id = blockIdx.x;
    const int ct = id >> 6, hb = id & 63;
    const int h = hb >> 4, b = hb & 15;
    const size_t wv_base = ((size_t)h * CC + ct * 128) * CC;
    const size_t x8_base = (size_t)(h * BB + b) * NP * CC;
    const size_t xh_base = x8_base;
    const size_t p_base  = (size_t)(h * BB + b) * NP * NP;

    // phase 1: V = Wv @ x (int8, K-step 64)
    i32x4 acc8[4][7];
    const i32x4 zi = {0, 0, 0, 0};
#pragma unroll
    for (int i = 0; i < 4; ++i)
#pragma unroll
        for (int j = 0; j < 7; ++j) acc8[i][j] = zi;

    for (int k0 = 0; k0 < CC; k0 += 64) {
#pragma unroll
        for (int it = 0; it < 2; ++it) {
            int cell = it * 256 + t;
            int g = cell >> 7, o = cell & 127;
            cp16(Aw8 + (size_t)cell * 16, Wv8 + wv_base + (size_t)o * CC + k0 + 16 * g);
        }
#pragma unroll
        for (int it = 0; it < 4; ++it) {
            int cell = it * 256 + t;
            if (cell < 896) {
                int g = cell / NP, n = cell % NP;
                cp16(Bx8 + (size_t)cell * 16, x8 + x8_base + (size_t)n * CC + k0 + 16 * g);
            }
        }
        __syncthreads();
        i32x4 a8[4], b8[7];
#pragma unroll
        for (int i = 0; i < 4; ++i)
            a8[i] = *(const i32x4*)(Aw8 + (size_t)(lg * 128 + wr * 64 + i * 16 + l16) * 16);
#pragma unroll
        for (int j = 0; j < 7; ++j)
            b8[j] = *(const i32x4*)(Bx8 + (size_t)(lg * NP + wc * 112 + j * 16 + l16) * 16);
#pragma unroll
        for (int i = 0; i < 4; ++i)
#pragma unroll
            for (int j = 0; j < 7; ++j)
                acc8[i][j] = __builtin_amdgcn_mfma_i32_16x16x64_i8(a8[i], b8[j], acc8[i][j], 0, 0, 0);
        __syncthreads();
    }

    // park V (dequant + bias) in LDS as bf16
#pragma unroll
    for (int i = 0; i < 4; ++i) {
        int cb = wr * 64 + i * 16 + lg * 4;
#pragma unroll
        for (int j = 0; j < 7; ++j) {
            int n = wc * 112 + j * 16 + l16;
#pragma unroll
            for (int r = 0; r < 4; ++r) {
                float v = (float)acc8[i][j][r] * SCL + bv[h * CC + ct * 128 + cb + r];
                Vb[(size_t)((n >> 3) * 128 + cb + r) * 8 + (n & 7)] = f2bf(v);
            }
        }
    }
    __syncthreads();

    // phase 2: out = V @ P^T (bf16)
    f32x4 acc[4][7];
    const f32x4 zf = {0.f, 0.f, 0.f, 0.f};
#pragma unroll
    for (int i = 0; i < 4; ++i)
#pragma unroll
        for (int j = 0; j < 7; ++j) acc[i][j] = zf;

    for (int s = 0; s < 7; ++s) {
#pragma unroll
        for (int it = 0; it < 4; ++it) {
            if (it < 3 || w < 2) {
                int cell = it * 256 + w * 64 + ln;
                int g = cell / NP, m = cell % NP;
                cp16(BxP + (size_t)cell * 8, atnb + p_base + (size_t)m * NP + s * 32 + 8 * g);
            }
        }
        __syncthreads();
        bf16x8 a[4], bq[7];
#pragma unroll
        for (int i = 0; i < 4; ++i)
            a[i] = *(const bf16x8*)(Vb + (size_t)((4 * s + lg) * 128 + wr * 64 + i * 16 + l16) * 8);
#pragma unroll
        for (int j = 0; j < 7; ++j)
            bq[j] = *(const bf16x8*)(BxP + (size_t)(lg * NP + wc * 112 + j * 16 + l16) * 8);
#pragma unroll
        for (int i = 0; i < 4; ++i)
#pragma unroll
            for (int j = 0; j < 7; ++j)
                acc[i][j] = __builtin_amdgcn_mfma_f32_16x16x32_bf16(a[i], bq[j], acc[i][j], 0, 0, 0);
        __syncthreads();
    }

    // epilogue
    const float gm = gamma[h];
    const size_t ob = ((size_t)(h * BB + b) * CC + ct * 128) * NN;
#pragma unroll
    for (int i = 0; i < 4; ++i) {
        int cb = wr * 64 + i * 16 + lg * 4;
#pragma unroll
        for (int j = 0; j < 7; ++j) {
            int m = wc * 112 + j * 16 + l16;
            if (m < NN) {
                const u16* xp = xhi + xh_base + (size_t)m * CC + ct * 128 + cb;
#pragma unroll
                for (int r = 0; r < 4; ++r) {
                    float ov = gm * acc[i][j][r] + bf2f(xp[r]);
                    outs[ob + (size_t)(cb + r) * NN + m] = f2bf(ov);
                }
            }
        }
    }
}

// ---------------------------------------------------------------- k_lin (MFMA, split-K)
// B-staging coalesced: thread t covers float4 fr=t&7 of rows rb, rb+32, ...
// Lanes 0-7 read 128 contiguous bytes of one Wl row -> 8x128B segs per wave.
__global__ __launch_bounds__(256, 2) void k_lin(
    const u16* __restrict__ feats, const float* __restrict__ Wl,
    float* __restrict__ part)
{
    __shared__ u16 lds[(256 + 1040) * 8];
    u16* Aa = lds;
    u16* Bb = lds + 256 * 8;
    const int t = threadIdx.x, w = t >> 6, ln = t & 63;
    const int lg = ln >> 4, l16 = ln & 15;
    const int wr = w >> 1, wc = w & 1;      // wave tile: 32 a x 128 dm
    const int dmt = blockIdx.x, ch = blockIdx.y;
    const int ga = t >> 6, aa = t & 63;
    const u16* asrc = feats + (size_t)((aa & 3) * BB + (aa >> 2)) * FF + (size_t)ch * 1568 + 8 * ga;
    const int fr = t & 7, rb = t >> 3;      // float4 idx, base row
    const int gB = fr >> 1, hB = fr & 1;    // LDS cell k-group, 8B half
    const float* bsrc = Wl + ((size_t)dmt * 256 + rb) * FF + (size_t)ch * 1568 + fr * 4;

    f32x4 acc[2][8];
    const f32x4 zf = {0.f, 0.f, 0.f, 0.f};
#pragma unroll
    for (int i = 0; i < 2; ++i)
#pragma unroll
        for (int j = 0; j < 8; ++j) acc[i][j] = zf;

    for (int k0 = 0; k0 < 1568; k0 += 32) {
        cp16(Aa + (size_t)t * 8, asrc + k0);
#pragma unroll
        for (int rr = 0; rr < 8; ++rr) {
            int row = rr * 32 + rb;
            float4 f = *(const float4*)(bsrc + (size_t)rr * 32 * FF + k0);
            u16x4 u;
            u.x = f2bf(f.x); u.y = f2bf(f.y); u.z = f2bf(f.z); u.w = f2bf(f.w);
            *(u16x4*)(Bb + ((size_t)(gB * 260 + row)) * 8 + hB * 4) = u;
        }
        __syncthreads();
        bf16x8 a[2], bq[8];
#pragma unroll
        for (int i = 0; i < 2; ++i)
            a[i] = *(const bf16x8*)(Aa + (size_t)(lg * 64 + wr * 32 + i * 16 + l16) * 8);
#pragma unroll
        for (int j = 0; j < 8; ++j)
            bq[j] = *(const bf16x8*)(Bb + (size_t)(lg * 260 + wc * 128 + j * 16 + l16) * 8);
#pragma unroll
        for (int i = 0; i < 2; ++i)
#pragma unroll
            for (int j = 0; j < 8; ++j)
                acc[i][j] = __builtin_amdgcn_mfma_f32_16x16x32_bf16(a[i], bq[j], acc[i][j], 0, 0, 0);
        __syncthreads();
    }
#pragma unroll
    for (int i = 0; i < 2; ++i)
#pragma unroll
        for (int j = 0; j < 8; ++j)
#pragma unroll
            for (int r = 0; r < 4; ++r)
                part[((size_t)ch * 64 + wr * 32 + i * 16 + lg * 4 + r) * DM
                     + dmt * 256 + wc * 128 + j * 16 + l16] = acc[i][j][r];
}

// ---------------------------------------------------------------- k_red
__global__ __launch_bounds__(256) void k_red(const float* __restrict__ part,
                                             const float* __restrict__ bl,
                                             float* __restrict__ out0)
{
    int gid = blockIdx.x * 256 + threadIdx.x;
    if (gid < 64 * DM) {
        int dm = gid & (DM - 1);
        float s = bl[dm];
        for (int c2 = 0; c2 < 256; ++c2) s += part[(size_t)c2 * 64 * DM + gid];
        out0[gid] = s;
    }
}

// ---------------------------------------------------------------- launch
extern "C" void kernel_launch(void* const* d_in, const int* in_sizes, int n_in,
                              void* d_out, int out_size, void* d_ws, size_t ws_size,
                              hipStream_t stream)
{
    const float* bef   = (const float*)d_in[0];
    const float* aft   = (const float*)d_in[1];
    const float* Wq    = (const float*)d_in[2];
    const float* bq    = (const float*)d_in[3];
    const float* Wk    = (const float*)d_in[4];
    const float* bk    = (const float*)d_in[5];
    const float* Wv    = (const float*)d_in[6];
    const float* bv    = (const float*)d_in[7];
    const float* gamma = (const float*)d_in[8];
    const float* Wl    = (const float*)d_in[9];
    const float* bl    = (const float*)d_in[10];

    float* out0   = (float*)d_out;
    float* alphas = out0 + (size_t)BB * HH * DM;

    float* ws = (float*)d_ws;
    u16* xhi  = (u16*)ws;                        // 14,680,064
    u16* xlo  = (u16*)(ws + 14680064);           // 14,680,064
    u16* dhi  = (u16*)(ws + 29360128);           //  3,670,016
    u16* dlo  = (u16*)(ws + 33030144);           //  3,670,016
    u16* wqh  = (u16*)(ws + 36700160);           //  1,048,576
    u16* wql  = (u16*)(ws + 37748736);
    u16* wkh  = (u16*)(ws + 38797312);
    u16* wkl  = (u16*)(ws + 39845888);
    u16* Qhb  = (u16*)(ws + 40894464);           //  1,835,008 each
    u16* Qlb  = (u16*)(ws + 42729472);
    u16* Khb  = (u16*)(ws + 44564480);
    u16* Klb  = (u16*)(ws + 46399488);
    s8*  Wv8  = (s8*)(ws + 48234496);            //  4,194,304
    s8*  x8   = (s8*)(ws + 52428800);            //  7,340,032
    u16* atnb = (u16*)(ws + 59768832);           //  1,605,632
    u16* outs = (u16*)(ws + 61374464);           // 12,845,056
    float* part = ws + 74219520;                 //  8,388,608 -> end 82,608,128

    k_prep<<<2048, 256, 0, stream>>>(bef, aft, xhi, xlo, dhi, dlo, x8);
    k_castW<<<2048, 256, 0, stream>>>(Wq, Wk, Wv, wqh, wql, wkh, wkl, Wv8);
    k_qkm<<<384, 256, 0, stream>>>(xhi, xlo, dhi, dlo, wqh, wql, wkh, wkl,
                                   bq, bk, Qhb, Qlb, Khb, Klb);
    k_esm<<<dim3(64, 4), 256, 0, stream>>>(Qhb, Qlb, Khb, Klb, alphas, atnb);
    k_vpv<<<1024, 256, 0, stream>>>(Wv8, x8, xhi, atnb, bv, gamma, outs);
    k_lin<<<dim3(2, 256), 256, 0, stream>>>(outs, Wl, part);
    k_red<<<128, 256, 0, stream>>>(part, bl, out0);
}

// Round 11
// 562.738 us; speedup vs baseline: 1.2149x; 1.0333x over previous
//
#include <hip/hip_runtime.h>
#include <hip/hip_bf16.h>

#define BB 16
#define NN 196
#define NP 224
#define CC 2048
#define C8 256
#define HH 4
#define DM 512
#define FF (CC*NN)   // 401408

typedef unsigned short u16;
typedef signed char s8;
typedef __attribute__((ext_vector_type(4))) u16 u16x4;
typedef __attribute__((ext_vector_type(8))) u16 u16x8;
typedef __attribute__((ext_vector_type(8))) short bf16x8;
typedef __attribute__((ext_vector_type(4))) float f32x4;
typedef __attribute__((ext_vector_type(4))) int i32x4;

typedef __attribute__((address_space(1))) unsigned int as1_uint;
typedef __attribute__((address_space(3))) unsigned int as3_uint;

__device__ __forceinline__ void cp16(void* l, const void* g) {
    __builtin_amdgcn_global_load_lds((as1_uint*)g, (as3_uint*)l, 16, 0, 0);
}

__device__ __forceinline__ u16 f2bf(float f) {
    union { float f; unsigned u; } x; x.f = f;
    unsigned r = x.u + 0x7FFF + ((x.u >> 16) & 1);
    return (u16)(r >> 16);
}
__device__ __forceinline__ float bf2f(u16 u) {
    union { unsigned u; float f; } x; x.u = ((unsigned)u) << 16;
    return x.f;
}
__device__ __forceinline__ int q8i(float v, float s) {
    int q = __float2int_rn(fminf(fmaxf(v * s, -127.f), 127.f));
    return q & 255;
}
__device__ __forceinline__ int pk4(float a, float b, float c, float d, float s) {
    return q8i(a, s) | (q8i(b, s) << 8) | (q8i(c, s) << 16) | (q8i(d, s) << 24);
}

#define QX (127.0f / 6.0f)
#define QW (127.0f / 0.15f)
#define SCL ((6.0f / 127.0f) * (0.15f / 127.0f))

// ---------------------------------------------------------------- k_prep
// x/d hi-lo splits + x8 int8 + (merged) Wq/Wk hi-lo splits
__global__ __launch_bounds__(256) void k_prep(const float* __restrict__ bef,
                                              const float* __restrict__ aft,
                                              const float* __restrict__ Wq,
                                              const float* __restrict__ Wk,
                                              u16* __restrict__ xhi, u16* __restrict__ xlo,
                                              u16* __restrict__ dhi, u16* __restrict__ dlo,
                                              s8* __restrict__ x8,
                                              u16* __restrict__ wqh, u16* __restrict__ wql,
                                              u16* __restrict__ wkh, u16* __restrict__ wkl)
{
    const float inv3 = 1.0f / 3.0f;
    const size_t n4 = (size_t)BB * NN * CC / 4;   // 1605632
    const size_t stride = (size_t)gridDim.x * blockDim.x;
    for (size_t i = (size_t)blockIdx.x * blockDim.x + threadIdx.x; i < n4; i += stride) {
        float4 a = ((const float4*)aft)[i];
        float4 b = ((const float4*)bef)[i];
        float4 d;
        d.x = (a.x - b.x) * inv3; d.y = (a.y - b.y) * inv3;
        d.z = (a.z - b.z) * inv3; d.w = (a.w - b.w) * inv3;
        size_t bn = i >> 9;
        int c = (int)(i & 511) * 4;
        int b_ = (int)(bn / NN), n = (int)(bn % NN);
        size_t dof = ((size_t)b_ * NP + n) * CC + c;
        u16x4 h4, l4;
        h4.x = f2bf(d.x); l4.x = f2bf(d.x - bf2f(h4.x));
        h4.y = f2bf(d.y); l4.y = f2bf(d.y - bf2f(h4.y));
        h4.z = f2bf(d.z); l4.z = f2bf(d.z - bf2f(h4.z));
        h4.w = f2bf(d.w); l4.w = f2bf(d.w - bf2f(h4.w));
        *(u16x4*)(dhi + dof) = h4;
        *(u16x4*)(dlo + dof) = l4;
#pragma unroll
        for (int h = 0; h < HH; ++h) {
            float fh = (float)h;
            float4 x;
            x.x = b.x + fh * d.x; x.y = b.y + fh * d.y;
            x.z = b.z + fh * d.z; x.w = b.w + fh * d.w;
            size_t xof = ((size_t)(h * BB + b_) * NP + n) * CC + c;
            u16x4 xh4;
            xh4.x = f2bf(x.x); xh4.y = f2bf(x.y);
            xh4.z = f2bf(x.z); xh4.w = f2bf(x.w);
            *(u16x4*)(xhi + xof) = xh4;
            if (h != 0) {
                u16x4 xl4;
                xl4.x = f2bf(x.x - bf2f(xh4.x));
                xl4.y = f2bf(x.y - bf2f(xh4.y));
                xl4.z = f2bf(x.z - bf2f(xh4.z));
                xl4.w = f2bf(x.w - bf2f(xh4.w));
                *(u16x4*)(xlo + xof) = xl4;
            }
            *(int*)(x8 + xof) = pk4(x.x, x.y, x.z, x.w, QX);
        }
    }
    // zero pad rows
    const size_t dpad = (size_t)BB * (NP - NN) * CC / 4;      // 229376
    const u16x4 z4 = {0, 0, 0, 0};
    for (size_t i = (size_t)blockIdx.x * blockDim.x + threadIdx.x; i < dpad; i += stride) {
        size_t b_ = i / ((NP - NN) * CC / 4);
        size_t rem = i % ((NP - NN) * CC / 4);
        int pn = (int)(rem >> 9), c4 = (int)(rem & 511);
        size_t of = ((size_t)b_ * NP + NN + pn) * CC + c4 * 4;
        *(u16x4*)(dhi + of) = z4; *(u16x4*)(dlo + of) = z4;
    }
    const size_t xpad = (size_t)HH * BB * (NP - NN) * CC / 4; // 917504
    for (size_t i = (size_t)blockIdx.x * blockDim.x + threadIdx.x; i < xpad; i += stride) {
        size_t hb = i / ((NP - NN) * CC / 4);
        size_t rem = i % ((NP - NN) * CC / 4);
        int pn = (int)(rem >> 9), c4 = (int)(rem & 511);
        size_t of = ((size_t)hb * NP + NN + pn) * CC + c4 * 4;
        *(u16x4*)(xhi + of) = z4; *(u16x4*)(xlo + of) = z4;
        *(int*)(x8 + of) = 0;
    }
    // merged castQK: Wq/Wk hi-lo splits
    const size_t qk = (size_t)HH * C8 * CC / 4;   // 524288
    for (size_t i = (size_t)blockIdx.x * blockDim.x + threadIdx.x; i < qk * 2; i += stride) {
        const float* src; u16* dh; u16* dl; size_t j;
        if (i < qk) { src = Wq; dh = wqh; dl = wql; j = i; }
        else        { src = Wk; dh = wkh; dl = wkl; j = i - qk; }
        float4 f = ((const float4*)src)[j];
        u16x4 h4, l4;
        h4.x = f2bf(f.x); l4.x = f2bf(f.x - bf2f(h4.x));
        h4.y = f2bf(f.y); l4.y = f2bf(f.y - bf2f(h4.y));
        h4.z = f2bf(f.z); l4.z = f2bf(f.z - bf2f(h4.z));
        h4.w = f2bf(f.w); l4.w = f2bf(f.w - bf2f(h4.w));
        ((u16x4*)dh)[j] = h4; ((u16x4*)dl)[j] = l4;
    }
}

// ---------------------------------------------------------------- k_qkm
// split-bf16 MFMA GEMM, BK=32, linear grid 512:
//   blocks 0..383: qkm (id = xid*96 + z*48 + j0; id%8 = j0%8 -> hb co-XCD)
//   blocks 384..511: castWv filler (Wv fp32 -> int8)
__global__ __launch_bounds__(256, 2) void k_qkm(
    const u16* __restrict__ xhi, const u16* __restrict__ xlo,
    const u16* __restrict__ dhi, const u16* __restrict__ dlo,
    const u16* __restrict__ wqh, const u16* __restrict__ wql,
    const u16* __restrict__ wkh, const u16* __restrict__ wkl,
    const float* __restrict__ bq, const float* __restrict__ bk,
    const float* __restrict__ Wv, s8* __restrict__ Wv8,
    u16* __restrict__ Qhb, u16* __restrict__ Qlb,
    u16* __restrict__ Khb, u16* __restrict__ Klb)
{
    // cells of 16B: Wh [0,512) Wl [512,1024) Xh [1024,1472) Xl [1472,1920)
    __shared__ u16 lds[1920 * 8];
    u16* Wh = lds;
    u16* Wl_ = lds + 512 * 8;
    u16* Xh = lds + 1024 * 8;
    u16* Xl = lds + 1472 * 8;

    const int t = threadIdx.x, w = t >> 6, ln = t & 63;
    const int lg = ln >> 4, l16 = ln & 15;
    const int id = blockIdx.x;

    if (id >= 384) {   // castWv filler
        const size_t wv4 = (size_t)HH * CC * CC / 4;   // 4194304
        for (size_t i = (size_t)(id - 384) * 256 + t; i < wv4; i += 128 * 256) {
            float4 f = ((const float4*)Wv)[i];
            *(int*)(Wv8 + 4 * i) = pk4(f.x, f.y, f.z, f.w, QW);
        }
        return;
    }

    const int xid = id / 96, rem = id % 96;
    const int z = rem / 48, j0 = rem % 48;
    const int hb = j0 + 16, h = hb >> 4, b = hb & 15;
    const int ct = xid & 1, mt = xid >> 1;   // mt in {0,1}

    const u16* Ah = (z ? dhi + (size_t)b * NP * CC : xhi + (size_t)hb * NP * CC)
                    + (size_t)(mt * 112) * CC;
    const u16* Al = (z ? dlo + (size_t)b * NP * CC : xlo + (size_t)hb * NP * CC)
                    + (size_t)(mt * 112) * CC;
    const u16* Bh = (z ? wkh : wqh) + ((size_t)h * C8 + ct * 128) * CC;
    const u16* Bl = (z ? wkl : wql) + ((size_t)h * C8 + ct * 128) * CC;
    const float scale = z ? (float)h : 1.0f;
    const float* bias = (z ? bk : bq) + h * C8;
    u16* OutH = z ? Khb : Qhb;
    u16* OutL = z ? Klb : Qlb;

    f32x4 acc[2][7];
    const f32x4 zf = {0.f, 0.f, 0.f, 0.f};
#pragma unroll
    for (int i = 0; i < 2; ++i)
#pragma unroll
        for (int j = 0; j < 7; ++j) acc[i][j] = zf;

    for (int k0 = 0; k0 < CC; k0 += 32) {
#pragma unroll
        for (int it = 0; it < 2; ++it) {
            int cell = it * 256 + t;
            int g = cell >> 7, o = cell & 127;
            cp16(Wh + (size_t)cell * 8, Bh + (size_t)o * CC + k0 + 8 * g);
            cp16(Wl_ + (size_t)cell * 8, Bl + (size_t)o * CC + k0 + 8 * g);
        }
        {
            int g = t / 112, n = t % 112;
            cp16(Xh + (size_t)t * 8, Ah + (size_t)n * CC + k0 + 8 * g);
            cp16(Xl + (size_t)t * 8, Al + (size_t)n * CC + k0 + 8 * g);
            if (t < 192) {
                int cell = 256 + t;
                int g2 = cell / 112, n2 = cell % 112;
                cp16(Xh + (size_t)cell * 8, Ah + (size_t)n2 * CC + k0 + 8 * g2);
                cp16(Xl + (size_t)cell * 8, Al + (size_t)n2 * CC + k0 + 8 * g2);
            }
        }
        __syncthreads();
        bf16x8 ah[2], al[2], bh[7], bl[7];
#pragma unroll
        for (int i = 0; i < 2; ++i) {
            ah[i] = *(const bf16x8*)(Wh + (size_t)(lg * 128 + w * 32 + i * 16 + l16) * 8);
            al[i] = *(const bf16x8*)(Wl_ + (size_t)(lg * 128 + w * 32 + i * 16 + l16) * 8);
        }
#pragma unroll
        for (int j = 0; j < 7; ++j) {
            bh[j] = *(const bf16x8*)(Xh + (size_t)(lg * 112 + j * 16 + l16) * 8);
            bl[j] = *(const bf16x8*)(Xl + (size_t)(lg * 112 + j * 16 + l16) * 8);
        }
#pragma unroll
        for (int i = 0; i < 2; ++i)
#pragma unroll
            for (int j = 0; j < 7; ++j)
                acc[i][j] = __builtin_amdgcn_mfma_f32_16x16x32_bf16(ah[i], bh[j], acc[i][j], 0, 0, 0);
#pragma unroll
        for (int i = 0; i < 2; ++i)
#pragma unroll
            for (int j = 0; j < 7; ++j)
                acc[i][j] = __builtin_amdgcn_mfma_f32_16x16x32_bf16(ah[i], bl[j], acc[i][j], 0, 0, 0);
#pragma unroll
        for (int i = 0; i < 2; ++i)
#pragma unroll
            for (int j = 0; j < 7; ++j)
                acc[i][j] = __builtin_amdgcn_mfma_f32_16x16x32_bf16(al[i], bh[j], acc[i][j], 0, 0, 0);
        __syncthreads();
    }

#pragma unroll
    for (int i = 0; i < 2; ++i) {
        int ob = ct * 128 + w * 32 + i * 16 + lg * 4;
#pragma unroll
        for (int j = 0; j < 7; ++j) {
            int n = mt * 112 + j * 16 + l16;
            u16x4 hv, lv;
#pragma unroll
            for (int r = 0; r < 4; ++r) {
                float v = scale * acc[i][j][r] + bias[ob + r];
                hv[r] = f2bf(v);
                lv[r] = f2bf(v - bf2f(hv[r]));
            }
            size_t of = ((size_t)hb * NP + n) * C8 + ob;
            *(u16x4*)(OutH + of) = hv;
            *(u16x4*)(OutL + of) = lv;
        }
    }
}

// ---------------------------------------------------------------- k_esm (MFMA)
__global__ __launch_bounds__(256, 2) void k_esm(
    const u16* __restrict__ Qh, const u16* __restrict__ Ql,
    const u16* __restrict__ Kh, const u16* __restrict__ Kl,
    float* __restrict__ alphas, u16* __restrict__ atnb)
{
    // cells of 16B: QH [0,256) QL [256,512) KH [512,1408) KL [1408,2304)
    __shared__ u16 lds[2304 * 8];
    u16* QHs = lds;
    u16* QLs = lds + 256 * 8;
    u16* KHs = lds + 512 * 8;
    u16* KLs = lds + 1408 * 8;

    const int t = threadIdx.x, w = t >> 6, ln = t & 63;
    const int lg = ln >> 4, l16 = ln & 15;
    const int hb = blockIdx.x, mt = blockIdx.y;
    const int h = hb >> 4, b = hb & 15;

    if (h == 0) {   // uniform attention
        const float uni = 1.0f / 196.0f;
        const u16 ub = f2bf(uni);
        for (int idx = t; idx < 64 * NP; idx += 256) {
            int m = mt * 64 + idx / NP;
            int n = idx % NP;
            if (m < NP) {
                atnb[((size_t)hb * NP + m) * NP + n] = (n < NN) ? ub : (u16)0;
                if (m < NN && n < NN)
                    alphas[(((size_t)b * NN + m) * NN + n) * HH + 0] = uni;
            }
        }
        return;
    }

    const size_t base = (size_t)hb * NP * C8;

    f32x4 e[14];
    const f32x4 zf = {0.f, 0.f, 0.f, 0.f};
#pragma unroll
    for (int j = 0; j < 14; ++j) e[j] = zf;

    for (int o0 = 0; o0 < C8; o0 += 32) {
        {
            int g = t >> 6, mr = t & 63;
            size_t src = base + (size_t)(mt * 64 + mr) * C8 + o0 + 8 * g;
            cp16(QHs + (size_t)t * 8, Qh + src);
            cp16(QLs + (size_t)t * 8, Ql + src);
        }
#pragma unroll
        for (int it = 0; it < 4; ++it) {
            int cell = it * 256 + t;
            if (cell < 896) {
                int g = cell / 224, n = cell % 224;
                size_t src = base + (size_t)n * C8 + o0 + 8 * g;
                cp16(KHs + (size_t)cell * 8, Kh + src);
                cp16(KLs + (size_t)cell * 8, Kl + src);
            }
        }
        __syncthreads();
        bf16x8 ah = *(const bf16x8*)(QHs + (size_t)(lg * 64 + w * 16 + l16) * 8);
        bf16x8 al = *(const bf16x8*)(QLs + (size_t)(lg * 64 + w * 16 + l16) * 8);
#pragma unroll
        for (int j = 0; j < 14; ++j) {
            bf16x8 bh = *(const bf16x8*)(KHs + (size_t)(lg * 224 + j * 16 + l16) * 8);
            bf16x8 bl = *(const bf16x8*)(KLs + (size_t)(lg * 224 + j * 16 + l16) * 8);
            e[j] = __builtin_amdgcn_mfma_f32_16x16x32_bf16(ah, bh, e[j], 0, 0, 0);
            e[j] = __builtin_amdgcn_mfma_f32_16x16x32_bf16(ah, bl, e[j], 0, 0, 0);
            e[j] = __builtin_amdgcn_mfma_f32_16x16x32_bf16(al, bh, e[j], 0, 0, 0);
        }
        __syncthreads();
    }

#pragma unroll
    for (int r = 0; r < 4; ++r) {
        float mx = -1e30f;
#pragma unroll
        for (int j = 0; j < 14; ++j) {
            int n = j * 16 + l16;
            if (n < NN) mx = fmaxf(mx, e[j][r]);
        }
#pragma unroll
        for (int off = 1; off <= 8; off <<= 1) mx = fmaxf(mx, __shfl_xor(mx, off));
        float p[14];
        float s = 0.f;
#pragma unroll
        for (int j = 0; j < 14; ++j) {
            int n = j * 16 + l16;
            if (n < NN) { p[j] = __expf(e[j][r] - mx); s += p[j]; }
            else p[j] = 0.f;
        }
#pragma unroll
        for (int off = 1; off <= 8; off <<= 1) s += __shfl_xor(s, off);
        const float inv = 1.0f / s;
        const int m = mt * 64 + w * 16 + lg * 4 + r;
        if (m < NP) {
            u16* arow = atnb + ((size_t)hb * NP + m) * NP;
#pragma unroll
            for (int j = 0; j < 14; ++j) {
                int n = j * 16 + l16;
                float a = p[j] * inv;
                arow[n] = f2bf(a);
                if (m < NN && n < NN)
                    alphas[(((size_t)b * NN + m) * NN + n) * HH + h] = a;
            }
        }
    }
}

// ---------------------------------------------------------------- k_vpv
__global__ __launch_bounds__(256, 2) void k_vpv(
    const s8* __restrict__ Wv8,    // [h][2048][2048] int8
    const s8* __restrict__ x8,     // [h][b][224][2048] int8
    const u16* __restrict__ xhi,   // [h][b][224][2048] bf16 (residual)
    const u16* __restrict__ atnb,  // [h][b][224][224] bf16
    const float* __restrict__ bv,
    const float* __restrict__ gamma,
    u16* __restrict__ outs)        // [h][b][2048][196] bf16
{
    __shared__ u16 lds[4992 * 8];
    s8* Aw8 = (s8*)lds;            // 512 cells * 16B
    s8* Bx8 = (s8*)lds + 8192;     // 896 cells * 16B
    u16* BxP = lds + 512 * 8;      // phase-2 P staging (aliases Bx8)
    u16* Vb  = lds + 1408 * 8;     // bf16 V park

    const int t = threadIdx.x, w = t >> 6, ln = t & 63;
    const int lg = ln >> 4, l16 = ln & 15;
    const int wr = w >> 1, wc = w & 1;
    const int id = blockIdx.x;
    const int ct = id >> 6, hb = id & 63;
    const int h = hb >> 4, b = hb & 15;
    const size_t wv_base = ((size_t)h * CC + ct * 128) * CC;
    const size_t x8_base = (size_t)(h * BB + b) * NP * CC;
    const size_t xh_base = x8_base;
    const size_t p_base  = (size_t)(h * BB + b) * NP * NP;

    // phase 1: V = Wv @ x (int8, K-step 64)
    i32x4 acc8[4][7];
    const i32x4 zi = {0, 0, 0, 0};
#pragma unroll
    for (int i = 0; i < 4; ++i)
#pragma unroll
        for (int j = 0; j < 7; ++j) acc8[i][j] = zi;

    for (int k0 = 0; k0 < CC; k0 += 64) {
#pragma unroll
        for (int it = 0; it < 2; ++it) {
            int cell = it * 256 + t;
            int g = cell >> 7, o = cell & 127;
            cp16(Aw8 + (size_t)cell * 16, Wv8 + wv_base + (size_t)o * CC + k0 + 16 * g);
        }
#pragma unroll
        for (int it = 0; it < 4; ++it) {
            int cell = it * 256 + t;
            if (cell < 896) {
                int g = cell / NP, n = cell % NP;
                cp16(Bx8 + (size_t)cell * 16, x8 + x8_base + (size_t)n * CC + k0 + 16 * g);
            }
        }
        __syncthreads();
        i32x4 a8[4], b8[7];
#pragma unroll
        for (int i = 0; i < 4; ++i)
            a8[i] = *(const i32x4*)(Aw8 + (size_t)(lg * 128 + wr * 64 + i * 16 + l16) * 16);
#pragma unroll
        for (int j = 0; j < 7; ++j)
            b8[j] = *(const i32x4*)(Bx8 + (size_t)(lg * NP + wc * 112 + j * 16 + l16) * 16);
#pragma unroll
        for (int i = 0; i < 4; ++i)
#pragma unroll
            for (int j = 0; j < 7; ++j)
                acc8[i][j] = __builtin_amdgcn_mfma_i32_16x16x64_i8(a8[i], b8[j], acc8[i][j], 0, 0, 0);
        __syncthreads();
    }

    // park V (dequant + bias) in LDS as bf16
#pragma unroll
    for (int i = 0; i < 4; ++i) {
        int cb = wr * 64 + i * 16 + lg * 4;
#pragma unroll
        for (int j = 0; j < 7; ++j) {
            int n = wc * 112 + j * 16 + l16;
#pragma unroll
            for (int r = 0; r < 4; ++r) {
                float v = (float)acc8[i][j][r] * SCL + bv[h * CC + ct * 128 + cb + r];
                Vb[(size_t)((n >> 3) * 128 + cb + r) * 8 + (n & 7)] = f2bf(v);
            }
        }
    }
    __syncthreads();

    // phase 2: out = V @ P^T (bf16)
    f32x4 acc[4][7];
    const f32x4 zf = {0.f, 0.f, 0.f, 0.f};
#pragma unroll
    for (int i = 0; i < 4; ++i)
#pragma unroll
        for (int j = 0; j < 7; ++j) acc[i][j] = zf;

    for (int s = 0; s < 7; ++s) {
#pragma unroll
        for (int it = 0; it < 4; ++it) {
            if (it < 3 || w < 2) {
                int cell = it * 256 + w * 64 + ln;
                int g = cell / NP, m = cell % NP;
                cp16(BxP + (size_t)cell * 8, atnb + p_base + (size_t)m * NP + s * 32 + 8 * g);
            }
        }
        __syncthreads();
        bf16x8 a[4], bq[7];
#pragma unroll
        for (int i = 0; i < 4; ++i)
            a[i] = *(const bf16x8*)(Vb + (size_t)((4 * s + lg) * 128 + wr * 64 + i * 16 + l16) * 8);
#pragma unroll
        for (int j = 0; j < 7; ++j)
            bq[j] = *(const bf16x8*)(BxP + (size_t)(lg * NP + wc * 112 + j * 16 + l16) * 8);
#pragma unroll
        for (int i = 0; i < 4; ++i)
#pragma unroll
            for (int j = 0; j < 7; ++j)
                acc[i][j] = __builtin_amdgcn_mfma_f32_16x16x32_bf16(a[i], bq[j], acc[i][j], 0, 0, 0);
        __syncthreads();
    }

    // epilogue
    const float gm = gamma[h];
    const size_t ob = ((size_t)(h * BB + b) * CC + ct * 128) * NN;
#pragma unroll
    for (int i = 0; i < 4; ++i) {
        int cb = wr * 64 + i * 16 + lg * 4;
#pragma unroll
        for (int j = 0; j < 7; ++j) {
            int m = wc * 112 + j * 16 + l16;
            if (m < NN) {
                const u16* xp = xhi + xh_base + (size_t)m * CC + ct * 128 + cb;
#pragma unroll
                for (int r = 0; r < 4; ++r) {
                    float ov = gm * acc[i][j][r] + bf2f(xp[r]);
                    outs[ob + (size_t)(cb + r) * NN + m] = f2bf(ov);
                }
            }
        }
    }
}

// ---------------------------------------------------------------- k_lin (MFMA, split-K)
// B-staging coalesced: thread t covers float4 fr=t&7 of rows rb, rb+32, ...
__global__ __launch_bounds__(256, 2) void k_lin(
    const u16* __restrict__ feats, const float* __restrict__ Wl,
    float* __restrict__ part)
{
    __shared__ u16 lds[(256 + 1040) * 8];
    u16* Aa = lds;
    u16* Bb = lds + 256 * 8;
    const int t = threadIdx.x, w = t >> 6, ln = t & 63;
    const int lg = ln >> 4, l16 = ln & 15;
    const int wr = w >> 1, wc = w & 1;      // wave tile: 32 a x 128 dm
    const int dmt = blockIdx.x, ch = blockIdx.y;
    const int ga = t >> 6, aa = t & 63;
    const u16* asrc = feats + (size_t)((aa & 3) * BB + (aa >> 2)) * FF + (size_t)ch * 1568 + 8 * ga;
    const int fr = t & 7, rb = t >> 3;      // float4 idx, base row
    const int gB = fr >> 1, hB = fr & 1;    // LDS cell k-group, 8B half
    const float* bsrc = Wl + ((size_t)dmt * 256 + rb) * FF + (size_t)ch * 1568 + fr * 4;

    f32x4 acc[2][8];
    const f32x4 zf = {0.f, 0.f, 0.f, 0.f};
#pragma unroll
    for (int i = 0; i < 2; ++i)
#pragma unroll
        for (int j = 0; j < 8; ++j) acc[i][j] = zf;

    for (int k0 = 0; k0 < 1568; k0 += 32) {
        cp16(Aa + (size_t)t * 8, asrc + k0);
#pragma unroll
        for (int rr = 0; rr < 8; ++rr) {
            int row = rr * 32 + rb;
            float4 f = *(const float4*)(bsrc + (size_t)rr * 32 * FF + k0);
            u16x4 u;
            u.x = f2bf(f.x); u.y = f2bf(f.y); u.z = f2bf(f.z); u.w = f2bf(f.w);
            *(u16x4*)(Bb + ((size_t)(gB * 260 + row)) * 8 + hB * 4) = u;
        }
        __syncthreads();
        bf16x8 a[2], bq[8];
#pragma unroll
        for (int i = 0; i < 2; ++i)
            a[i] = *(const bf16x8*)(Aa + (size_t)(lg * 64 + wr * 32 + i * 16 + l16) * 8);
#pragma unroll
        for (int j = 0; j < 8; ++j)
            bq[j] = *(const bf16x8*)(Bb + (size_t)(lg * 260 + wc * 128 + j * 16 + l16) * 8);
#pragma unroll
        for (int i = 0; i < 2; ++i)
#pragma unroll
            for (int j = 0; j < 8; ++j)
                acc[i][j] = __builtin_amdgcn_mfma_f32_16x16x32_bf16(a[i], bq[j], acc[i][j], 0, 0, 0);
        __syncthreads();
    }
#pragma unroll
    for (int i = 0; i < 2; ++i)
#pragma unroll
        for (int j = 0; j < 8; ++j)
#pragma unroll
            for (int r = 0; r < 4; ++r)
                part[((size_t)ch * 64 + wr * 32 + i * 16 + lg * 4 + r) * DM
                     + dmt * 256 + wc * 128 + j * 16 + l16] = acc[i][j][r];
}

// ---------------------------------------------------------------- k_red
__global__ __launch_bounds__(256) void k_red(const float* __restrict__ part,
                                             const float* __restrict__ bl,
                                             float* __restrict__ out0)
{
    int gid = blockIdx.x * 256 + threadIdx.x;
    if (gid < 64 * DM) {
        int dm = gid & (DM - 1);
        float s = bl[dm];
        for (int c2 = 0; c2 < 256; ++c2) s += part[(size_t)c2 * 64 * DM + gid];
        out0[gid] = s;
    }
}

// ---------------------------------------------------------------- launch
extern "C" void kernel_launch(void* const* d_in, const int* in_sizes, int n_in,
                              void* d_out, int out_size, void* d_ws, size_t ws_size,
                              hipStream_t stream)
{
    const float* bef   = (const float*)d_in[0];
    const float* aft   = (const float*)d_in[1];
    const float* Wq    = (const float*)d_in[2];
    const float* bq    = (const float*)d_in[3];
    const float* Wk    = (const float*)d_in[4];
    const float* bk    = (const float*)d_in[5];
    const float* Wv    = (const float*)d_in[6];
    const float* bv    = (const float*)d_in[7];
    const float* gamma = (const float*)d_in[8];
    const float* Wl    = (const float*)d_in[9];
    const float* bl    = (const float*)d_in[10];

    float* out0   = (float*)d_out;
    float* alphas = out0 + (size_t)BB * HH * DM;

    float* ws = (float*)d_ws;
    u16* xhi  = (u16*)ws;                        // 14,680,064
    u16* xlo  = (u16*)(ws + 14680064);           // 14,680,064
    u16* dhi  = (u16*)(ws + 29360128);           //  3,670,016
    u16* dlo  = (u16*)(ws + 33030144);           //  3,670,016
    u16* wqh  = (u16*)(ws + 36700160);           //  1,048,576
    u16* wql  = (u16*)(ws + 37748736);
    u16* wkh  = (u16*)(ws + 38797312);
    u16* wkl  = (u16*)(ws + 39845888);
    u16* Qhb  = (u16*)(ws + 40894464);           //  1,835,008 each
    u16* Qlb  = (u16*)(ws + 42729472);
    u16* Khb  = (u16*)(ws + 44564480);
    u16* Klb  = (u16*)(ws + 46399488);
    s8*  Wv8  = (s8*)(ws + 48234496);            //  4,194,304
    s8*  x8   = (s8*)(ws + 52428800);            //  7,340,032
    u16* atnb = (u16*)(ws + 59768832);           //  1,605,632
    u16* outs = (u16*)(ws + 61374464);           // 12,845,056
    float* part = ws + 74219520;                 //  8,388,608 -> end 82,608,128

    k_prep<<<2048, 256, 0, stream>>>(bef, aft, Wq, Wk, xhi, xlo, dhi, dlo, x8,
                                     wqh, wql, wkh, wkl);
    k_qkm<<<512, 256, 0, stream>>>(xhi, xlo, dhi, dlo, wqh, wql, wkh, wkl,
                                   bq, bk, Wv, Wv8, Qhb, Qlb, Khb, Klb);
    k_esm<<<dim3(64, 4), 256, 0, stream>>>(Qhb, Qlb, Khb, Klb, alphas, atnb);
    k_vpv<<<1024, 256, 0, stream>>>(Wv8, x8, xhi, atnb, bv, gamma, outs);
    k_lin<<<dim3(2, 256), 256, 0, stream>>>(outs, Wl, part);
    k_red<<<128, 256, 0, stream>>>(part, bl, out0);
}